// Round 6
// baseline (105.454 us; speedup 1.0000x reference)
//
#include <hip/hip_runtime.h>

// Fused upfirdn2d: up2(FIR12,H) -> up2(FIR12,W) -> +bias -> lrelu*sqrt2
//                  -> down2(FIR12,H) -> down2(FIR12,W)
// x: (32,128,64,64) f32.  Two half-slice blocks per (n,c), NT=640.
// R6: merge upW+lrelu+downW into one register-resident phase:
//   z --(6 b128 reads)--> 26 y values in regs --> 8 yw outputs --> 2 b128 writes.
//   Kills the 43.8KB y buffer and one barrier; LDS 45KB -> 3 blocks/CU.
//   lrelu via abs-trick: g*lrelu(a) = 0.6g*a + 0.4g*|a|; bias = acc init.
//
// Index math:
//   z[i][c]  = sum_{j == i (mod 2)} (2*fu[j]) * x[(i-j)/2][c]
//   y[i][w]  = sum_{j == w (mod 2)} (2*fu[j]) * z[i][(w-j)/2]; lrelu(y+b)*g
//   yw[i][p] = sum_{j} fd[j] * y[i][2p+11-j]          (down-W first; commutes)
//   out[o][p]= sum_{j} fd[j] * yw[2o+11-j][p]         (down-H second)

#define NT 640
#define GAIN 1.41421356237309504880f
#define C1 (0.6f * GAIN)
#define C2 (0.4f * GAIN)

#define ZROWS 74
#define ZSTRIDE 84            // 336B = 80B mod 128 -> full bank rotation, row-walk
#define ZPAD 8                // local col p <-> real z col p-8 ; pads zeroed
#define YWSTRIDE 68           // 272B = 16B mod 128 -> full bank rotation, row-walk

#define ZB_OFF 0
#define YW_OFF (ZROWS * ZSTRIDE)               // 6216
#define LDS_FLOATS (YW_OFF + ZROWS * YWSTRIDE) // 11248 floats = 44992 B -> 3 blk/CU

__global__ __launch_bounds__(NT, 8) void fused_upfirdn_lrelu(
    const float* __restrict__ x,
    const float* __restrict__ bias,
    const float* __restrict__ upf,
    const float* __restrict__ dnf,
    float* __restrict__ out)
{
    extern __shared__ float lds[];
    float* zb = lds + ZB_OFF;
    float* yw = lds + YW_OFF;

    const int t = threadIdx.x;
    const int bid = blockIdx.x;
    const int s = bid >> 1;           // slice = n*128 + c
    const int o0 = (bid & 1) << 5;    // 0 or 32
    const int c = s & 127;

    float fu[12], fd[12];
#pragma unroll
    for (int j = 0; j < 12; ++j) { fu[j] = 2.0f * upf[j]; fd[j] = dnf[j]; }
    const float bv = bias[c];

    const float* xg = x + (size_t)s * 4096;
    float* outg = out + (size_t)s * 4096;

    // ---- Phase 1: up-H from GLOBAL x -> z rows [0,74) (t<304);
    //      threads 304..639 zero the pad columns. ----
    if (t < 304) {
        const int k = t >> 4;                 // 0..18 ; z local rows 4k..4k+3
        const int c4 = (t & 15) << 2;
        const int rbase = o0 - 5 + 2 * k;     // x rows rbase..rbase+6
        float4 xv[7];
#pragma unroll
        for (int d = 0; d < 7; ++d) {
            const int r = rbase + d;
            if (r >= 0 && r <= 63)
                xv[d] = *reinterpret_cast<const float4*>(xg + r * 64 + c4);
            else
                xv[d] = make_float4(0.f, 0.f, 0.f, 0.f);
        }
        float a0[4] = {0,0,0,0}, a1[4] = {0,0,0,0}, b0[4] = {0,0,0,0}, b1[4] = {0,0,0,0};
#pragma unroll
        for (int d = 0; d < 6; ++d) {         // rows 4k,4k+1 use xv[0..5], tt = 5-d
            const float w0 = fu[2 * (5 - d)], w1 = fu[2 * (5 - d) + 1];
            a0[0] += w0 * xv[d].x; a0[1] += w0 * xv[d].y; a0[2] += w0 * xv[d].z; a0[3] += w0 * xv[d].w;
            a1[0] += w1 * xv[d].x; a1[1] += w1 * xv[d].y; a1[2] += w1 * xv[d].z; a1[3] += w1 * xv[d].w;
        }
#pragma unroll
        for (int d = 1; d < 7; ++d) {         // rows 4k+2,4k+3 use xv[1..6], tt = 6-d
            const float w0 = fu[2 * (6 - d)], w1 = fu[2 * (6 - d) + 1];
            b0[0] += w0 * xv[d].x; b0[1] += w0 * xv[d].y; b0[2] += w0 * xv[d].z; b0[3] += w0 * xv[d].w;
            b1[0] += w1 * xv[d].x; b1[1] += w1 * xv[d].y; b1[2] += w1 * xv[d].z; b1[3] += w1 * xv[d].w;
        }
        float* zr = zb + (4 * k) * ZSTRIDE + ZPAD + c4;
        *reinterpret_cast<float4*>(zr)               = make_float4(a0[0], a0[1], a0[2], a0[3]);
        *reinterpret_cast<float4*>(zr + ZSTRIDE)     = make_float4(a1[0], a1[1], a1[2], a1[3]);
        if (k < 18) {
            *reinterpret_cast<float4*>(zr + 2 * ZSTRIDE) = make_float4(b0[0], b0[1], b0[2], b0[3]);
            *reinterpret_cast<float4*>(zr + 3 * ZSTRIDE) = make_float4(b1[0], b1[1], b1[2], b1[3]);
        }
    } else {
        // zero z pad cols [0,8) and [72,84): 5 float4 per row x 74 rows = 370 tasks
        for (int pt = t - 304; pt < 370; pt += 336) {
            const int rl = pt / 5;
            const int p = pt - rl * 5;
            const int col = (p < 2) ? (p << 2) : (72 + ((p - 2) << 2));
            *reinterpret_cast<float4*>(zb + rl * ZSTRIDE + col) = make_float4(0.f, 0.f, 0.f, 0.f);
        }
    }
    __syncthreads();

    // ---- Phase 2 (merged upW+lrelu+downW): per task = (cg, il):
    //      read z[il][8cg-5 .. 8cg+15] (6 b128), compute y[16cg .. 16cg+25]
    //      in regs, reduce to yw[il][8cg .. 8cg+7], write 2 b128. ----
    {
        const int cg = t / 80;                // 0..7 ; il fast-varying, padded to 80
        const int il = t - cg * 80;
        if (il < ZROWS) {
            const float* zr = zb + il * ZSTRIDE + (cg << 3);   // local col 8cg = real col 8cg-8
            float zv[24];
#pragma unroll
            for (int q = 0; q < 6; ++q) {
                const float4 v = *reinterpret_cast<const float4*>(zr + (q << 2));
                zv[4 * q] = v.x; zv[4 * q + 1] = v.y; zv[4 * q + 2] = v.z; zv[4 * q + 3] = v.w;
            }
            // y[u] for u = 0..25 (global w = 16cg+u):
            //   u=2v:   sum_tt fu[2tt]  *z[8cg+v-tt]  -> zv[v+8-tt]
            //   u=2v+1: sum_tt fu[2tt+1]*z[8cg+v-tt]
            float yv[26];
#pragma unroll
            for (int v = 0; v < 13; ++v) {
                float a0 = bv, a1 = bv;
#pragma unroll
                for (int tt = 0; tt < 6; ++tt) {
                    const float zz = zv[v + 8 - tt];
                    a0 += fu[2 * tt]     * zz;
                    a1 += fu[2 * tt + 1] * zz;
                }
                yv[2 * v]     = C1 * a0 + C2 * fabsf(a0);   // g*lrelu(a0)
                yv[2 * v + 1] = C1 * a1 + C2 * fabsf(a1);
            }
            float acc[8];
#pragma unroll
            for (int e = 0; e < 8; ++e) {     // yw[p=8cg+e] = sum_j fd[j]*y[u=2e+11-j]
                float a = 0.0f;
#pragma unroll
                for (int j = 0; j < 12; ++j) a += fd[j] * yv[2 * e + 11 - j];
                acc[e] = a;
            }
            float* wr = yw + il * YWSTRIDE + (cg << 3);
            *reinterpret_cast<float4*>(wr)     = make_float4(acc[0], acc[1], acc[2], acc[3]);
            *reinterpret_cast<float4*>(wr + 4) = make_float4(acc[4], acc[5], acc[6], acc[7]);
        }
    }
    __syncthreads();

    // ---- Phase 3: down-H on yw -> GLOBAL out.  t<128: 4 out rows x 4 cols
    //      from 18 yw rows. ----
    if (t < 128) {
        const int eg = t >> 4;                // 0..7 ; out rows 4eg..4eg+3
        const int col4 = (t & 15) << 2;       // 0..60
        const float* wr = yw + (eg << 3) * YWSTRIDE + col4;    // yw rows 8eg..8eg+17
        float acc[4][4] = {{0,0,0,0},{0,0,0,0},{0,0,0,0},{0,0,0,0}};
#pragma unroll
        for (int r = 0; r < 18; ++r) {
            const float4 v = *reinterpret_cast<const float4*>(wr + r * YWSTRIDE);
#pragma unroll
            for (int e = 0; e < 4; ++e) {
                if (r >= 2 * e && r <= 2 * e + 11) {           // compile-time per (r,e)
                    const float ww = fd[11 - r + 2 * e];
                    acc[e][0] += ww * v.x; acc[e][1] += ww * v.y;
                    acc[e][2] += ww * v.z; acc[e][3] += ww * v.w;
                }
            }
        }
#pragma unroll
        for (int e = 0; e < 4; ++e)
            *reinterpret_cast<float4*>(outg + (o0 + (eg << 2) + e) * 64 + col4) =
                make_float4(acc[e][0], acc[e][1], acc[e][2], acc[e][3]);
    }
}

extern "C" void kernel_launch(void* const* d_in, const int* in_sizes, int n_in,
                              void* d_out, int out_size, void* d_ws, size_t ws_size,
                              hipStream_t stream) {
    const float* x    = (const float*)d_in[0];
    const float* bias = (const float*)d_in[1];
    const float* upf  = (const float*)d_in[2];
    const float* dnf  = (const float*)d_in[3];
    float* out = (float*)d_out;

    const int n_blocks = 32 * 128 * 2;   // two half-slices per (n,c)
    const size_t lds_bytes = (size_t)LDS_FLOATS * sizeof(float);
    hipLaunchKernelGGL(fused_upfirdn_lrelu, dim3(n_blocks), dim3(NT),
                       lds_bytes, stream, x, bias, upf, dnf, out);
}

// Round 7
// 83.301 us; speedup vs baseline: 1.2659x; 1.2659x over previous
//
#include <hip/hip_runtime.h>

// Fused upfirdn2d: up2(FIR12,H) -> up2(FIR12,W) -> +bias -> lrelu*sqrt2
//                  -> down2(FIR12,H) -> down2(FIR12,W)
// x: (32,128,64,64) f32.  Two half-slice blocks per (n,c), NT=640.
// R7 = R6 merge (upW+lrelu+downW register-resident, no y buffer) with the
// spill fixed:
//   - y values are consumed immediately into acc[8] (no yv[26] array)
//   - filters/bias forced to SGPRs via readfirstlane (wave-uniform)
//   R6's WRITE_SIZE blowup (64->297MB) was scratch spill: live set > 64 VGPR.
//
// Index math:
//   z[i][c]  = sum_{j == i (mod 2)} (2*fu[j]) * x[(i-j)/2][c]
//   y[i][w]  = sum_{j == w (mod 2)} (2*fu[j]) * z[i][(w-j)/2]; lrelu(y+b)*g
//   yw[i][p] = sum_{j} fd[j] * y[i][2p+11-j]          (down-W first; commutes)
//   out[o][p]= sum_{j} fd[j] * yw[2o+11-j][p]         (down-H second)

#define NT 640
#define GAIN 1.41421356237309504880f
#define C1 (0.6f * GAIN)
#define C2 (0.4f * GAIN)

#define ZROWS 74
#define ZSTRIDE 84            // 336B = 80B mod 128 -> full bank rotation, row-walk
#define ZPAD 8                // local col p <-> real z col p-8 ; pads zeroed
#define YWSTRIDE 68           // 272B = 16B mod 128 -> full bank rotation, row-walk

#define ZB_OFF 0
#define YW_OFF (ZROWS * ZSTRIDE)               // 6216
#define LDS_FLOATS (YW_OFF + ZROWS * YWSTRIDE) // 11248 floats = 44992 B -> 3 blk/CU

// wave-uniform float -> SGPR
__device__ __forceinline__ float sload(float v) {
    return __uint_as_float(__builtin_amdgcn_readfirstlane(__float_as_uint(v)));
}

__global__ __launch_bounds__(NT, 8) void fused_upfirdn_lrelu(
    const float* __restrict__ x,
    const float* __restrict__ bias,
    const float* __restrict__ upf,
    const float* __restrict__ dnf,
    float* __restrict__ out)
{
    extern __shared__ float lds[];
    float* zb = lds + ZB_OFF;
    float* yw = lds + YW_OFF;

    const int t = threadIdx.x;
    const int bid = blockIdx.x;
    const int s = bid >> 1;           // slice = n*128 + c
    const int o0 = (bid & 1) << 5;    // 0 or 32
    const int c = s & 127;

    // filters + bias in SGPRs (uniform); fu pre-scaled by UP=2
    float fu[12], fd[12];
#pragma unroll
    for (int j = 0; j < 12; ++j) {
        fu[j] = sload(2.0f * upf[j]);
        fd[j] = sload(dnf[j]);
    }
    const float bv = sload(bias[c]);

    const float* xg = x + (size_t)s * 4096;
    float* outg = out + (size_t)s * 4096;

    // ---- Phase 1: up-H from GLOBAL x -> z rows [0,74) (t<304);
    //      threads 304..639 zero the pad columns. ----
    if (t < 304) {
        const int k = t >> 4;                 // 0..18 ; z local rows 4k..4k+3
        const int c4 = (t & 15) << 2;
        const int rbase = o0 - 5 + 2 * k;     // x rows rbase..rbase+6
        float4 xv[7];
#pragma unroll
        for (int d = 0; d < 7; ++d) {
            const int r = rbase + d;
            if (r >= 0 && r <= 63)
                xv[d] = *reinterpret_cast<const float4*>(xg + r * 64 + c4);
            else
                xv[d] = make_float4(0.f, 0.f, 0.f, 0.f);
        }
        float a0[4] = {0,0,0,0}, a1[4] = {0,0,0,0}, b0[4] = {0,0,0,0}, b1[4] = {0,0,0,0};
#pragma unroll
        for (int d = 0; d < 6; ++d) {         // rows 4k,4k+1 use xv[0..5], tt = 5-d
            const float w0 = fu[2 * (5 - d)], w1 = fu[2 * (5 - d) + 1];
            a0[0] += w0 * xv[d].x; a0[1] += w0 * xv[d].y; a0[2] += w0 * xv[d].z; a0[3] += w0 * xv[d].w;
            a1[0] += w1 * xv[d].x; a1[1] += w1 * xv[d].y; a1[2] += w1 * xv[d].z; a1[3] += w1 * xv[d].w;
        }
#pragma unroll
        for (int d = 1; d < 7; ++d) {         // rows 4k+2,4k+3 use xv[1..6], tt = 6-d
            const float w0 = fu[2 * (6 - d)], w1 = fu[2 * (6 - d) + 1];
            b0[0] += w0 * xv[d].x; b0[1] += w0 * xv[d].y; b0[2] += w0 * xv[d].z; b0[3] += w0 * xv[d].w;
            b1[0] += w1 * xv[d].x; b1[1] += w1 * xv[d].y; b1[2] += w1 * xv[d].z; b1[3] += w1 * xv[d].w;
        }
        float* zr = zb + (4 * k) * ZSTRIDE + ZPAD + c4;
        *reinterpret_cast<float4*>(zr)               = make_float4(a0[0], a0[1], a0[2], a0[3]);
        *reinterpret_cast<float4*>(zr + ZSTRIDE)     = make_float4(a1[0], a1[1], a1[2], a1[3]);
        if (k < 18) {
            *reinterpret_cast<float4*>(zr + 2 * ZSTRIDE) = make_float4(b0[0], b0[1], b0[2], b0[3]);
            *reinterpret_cast<float4*>(zr + 3 * ZSTRIDE) = make_float4(b1[0], b1[1], b1[2], b1[3]);
        }
    } else {
        // zero z pad cols [0,8) and [72,84): 5 float4 per row x 74 rows = 370 tasks
        for (int pt = t - 304; pt < 370; pt += 336) {
            const int rl = pt / 5;
            const int p = pt - rl * 5;
            const int col = (p < 2) ? (p << 2) : (72 + ((p - 2) << 2));
            *reinterpret_cast<float4*>(zb + rl * ZSTRIDE + col) = make_float4(0.f, 0.f, 0.f, 0.f);
        }
    }
    __syncthreads();

    // ---- Phase 2 (merged upW+lrelu+downW): task = (cg, il):
    //      6 b128 z-reads -> y pairs computed and IMMEDIATELY folded into
    //      acc[8] (no y array) -> 2 b128 yw writes. ----
    {
        const int cg = t / 80;                // 0..7 ; il fast-varying, padded to 80
        const int il = t - cg * 80;
        if (il < ZROWS) {
            const float* zr = zb + il * ZSTRIDE + (cg << 3);   // local col 8cg = real col 8cg-8
            float zv[24];
#pragma unroll
            for (int q = 0; q < 6; ++q) {
                const float4 v = *reinterpret_cast<const float4*>(zr + (q << 2));
                zv[4 * q] = v.x; zv[4 * q + 1] = v.y; zv[4 * q + 2] = v.z; zv[4 * q + 3] = v.w;
            }
            float acc[8] = {0, 0, 0, 0, 0, 0, 0, 0};
#pragma unroll
            for (int v = 0; v < 13; ++v) {    // y[2v], y[2v+1]  (w = 16cg + u)
                float a0 = bv, a1 = bv;
#pragma unroll
                for (int tt = 0; tt < 6; ++tt) {
                    const float zz = zv[v + 8 - tt];
                    a0 += fu[2 * tt]     * zz;
                    a1 += fu[2 * tt + 1] * zz;
                }
                const float y0 = C1 * a0 + C2 * fabsf(a0);   // g*lrelu(y[2v])
                const float y1 = C1 * a1 + C2 * fabsf(a1);   // g*lrelu(y[2v+1])
                // y[u] -> acc[e] with tap j = 2e+11-u (compile-time per (v,e))
#pragma unroll
                for (int e = 0; e < 8; ++e) {
                    const int j0 = 2 * e + 11 - 2 * v;       // for y0 (u=2v)
                    const int j1 = 2 * e + 10 - 2 * v;       // for y1 (u=2v+1)
                    if (j0 >= 0 && j0 <= 11) acc[e] += fd[j0] * y0;
                    if (j1 >= 0 && j1 <= 11) acc[e] += fd[j1] * y1;
                }
            }
            float* wr = yw + il * YWSTRIDE + (cg << 3);
            *reinterpret_cast<float4*>(wr)     = make_float4(acc[0], acc[1], acc[2], acc[3]);
            *reinterpret_cast<float4*>(wr + 4) = make_float4(acc[4], acc[5], acc[6], acc[7]);
        }
    }
    __syncthreads();

    // ---- Phase 3: down-H on yw -> GLOBAL out.  t<128: 4 out rows x 4 cols
    //      from 18 yw rows. ----
    if (t < 128) {
        const int eg = t >> 4;                // 0..7 ; out rows 4eg..4eg+3
        const int col4 = (t & 15) << 2;       // 0..60
        const float* wr = yw + (eg << 3) * YWSTRIDE + col4;    // yw rows 8eg..8eg+17
        float acc[4][4] = {{0,0,0,0},{0,0,0,0},{0,0,0,0},{0,0,0,0}};
#pragma unroll
        for (int r = 0; r < 18; ++r) {
            const float4 v = *reinterpret_cast<const float4*>(wr + r * YWSTRIDE);
#pragma unroll
            for (int e = 0; e < 4; ++e) {
                if (r >= 2 * e && r <= 2 * e + 11) {           // compile-time per (r,e)
                    const float ww = fd[11 - r + 2 * e];
                    acc[e][0] += ww * v.x; acc[e][1] += ww * v.y;
                    acc[e][2] += ww * v.z; acc[e][3] += ww * v.w;
                }
            }
        }
#pragma unroll
        for (int e = 0; e < 4; ++e)
            *reinterpret_cast<float4*>(outg + (o0 + (eg << 2) + e) * 64 + col4) =
                make_float4(acc[e][0], acc[e][1], acc[e][2], acc[e][3]);
    }
}

extern "C" void kernel_launch(void* const* d_in, const int* in_sizes, int n_in,
                              void* d_out, int out_size, void* d_ws, size_t ws_size,
                              hipStream_t stream) {
    const float* x    = (const float*)d_in[0];
    const float* bias = (const float*)d_in[1];
    const float* upf  = (const float*)d_in[2];
    const float* dnf  = (const float*)d_in[3];
    float* out = (float*)d_out;

    const int n_blocks = 32 * 128 * 2;   // two half-slices per (n,c)
    const size_t lds_bytes = (size_t)LDS_FLOATS * sizeof(float);
    hipLaunchKernelGGL(fused_upfirdn_lrelu, dim3(n_blocks), dim3(NT),
                       lds_bytes, stream, x, bias, upf, dnf, out);
}